// Round 3
// baseline (204.254 us; speedup 1.0000x reference)
//
#include <hip/hip_runtime.h>
#include <hip/hip_bf16.h>

typedef __bf16 bf16x8 __attribute__((ext_vector_type(8)));
typedef __bf16 bf16x4 __attribute__((ext_vector_type(4)));
typedef float f32x4 __attribute__((ext_vector_type(4)));

#define NEG_INF (-__builtin_inff())

#define BAR() do { asm volatile("" ::: "memory"); __builtin_amdgcn_s_barrier(); asm volatile("" ::: "memory"); } while (0)

// ---------------------------------------------------------------------------
// f32 -> bf16 conversion (vectorized, grid-stride)
// ---------------------------------------------------------------------------
__global__ void cvt_f32_bf16(const float* __restrict__ src, __bf16* __restrict__ dst, int n) {
    int idx = blockIdx.x * blockDim.x + threadIdx.x;
    int stride = gridDim.x * blockDim.x;
    for (int i = idx * 4; i < n; i += stride * 4) {
        float4 v = *(const float4*)(src + i);
        bf16x4 o;
        o[0] = (__bf16)v.x; o[1] = (__bf16)v.y; o[2] = (__bf16)v.z; o[3] = (__bf16)v.w;
        *(bf16x4*)(dst + i) = o;
    }
}

// ---------------------------------------------------------------------------
// 8-phase 256x256 GEMM (BK=64, 512 threads = 8 waves as 2Mx4N).
// out[m][n] = sum_k A[m][k] * B[n][k]  (A: [M][K] bf16, B: [N][K] bf16).
// LDS 128 KiB: 2 buffers x (A 256x64 | B 256x64) bf16, staged by
// global_load_lds w16 with linear dest + involution-swizzled source;
// ds_read_b128 with the same swizzle. Counted vmcnt(2) at phases 4/8 only.
// MODE 0: bf16 out scattered to QKV layout; Q scaled 1/8; V transposed.
// MODE 1: f32 out row-major [M][N].
// ---------------------------------------------------------------------------
template <int MODE>
__launch_bounds__(512, 2)
__global__ void gemm8(const __bf16* __restrict__ A, const __bf16* __restrict__ Bm,
                      void* __restrict__ Out, int M, int N, int K) {
    __shared__ __align__(1024) char smem[131072];
    const int tid = threadIdx.x;
    const int w = tid >> 6, lane = tid & 63;
    const int lr = lane & 15, lg = lane >> 4;
    const int wr = w >> 2, wc = w & 3;

    // bijective XCD swizzle (nwg % 8 == 0 for both call sites)
    const int nbx = gridDim.x;
    int id = blockIdx.y * nbx + blockIdx.x;
    int q8 = (nbx * gridDim.y) >> 3;
    int vid = (id & 7) * q8 + (id >> 3);
    const int m0 = (vid / nbx) * 256, n0 = (vid % nbx) * 256;

    const char* Ab = (const char*)A;
    const char* Bb = (const char*)Bm;

    f32x4 acc[8][4] = {};
    bf16x8 af[4][2], bl[2][2], bh[2][2];

    // stage one 16KB piece (p: 0=A rows 0-127, 1=A rows 128-255, 2=B lo, 3=B hi)
    // of K-tile t into buffer `buf`. Linear LDS dest; source pre-swizzled.
    auto stage = [&](int p, int t, int buf) {
#pragma unroll
        for (int i = 0; i < 2; ++i) {
            unsigned drel = (unsigned)(((p & 1) << 14) + (w * 2 + i) * 1024 + lane * 16);
            unsigned s = drel ^ (((drel >> 7) & 7) << 4);
            unsigned srow = s >> 7, scolb = s & 127;
            char* dst = smem + buf * 65536 + ((p < 2) ? 0 : 32768) + drel;
            const char* src = (p < 2)
                ? Ab + ((size_t)(m0 + srow) * K + t * 64) * 2 + scolb
                : Bb + ((size_t)(n0 + srow) * K + t * 64) * 2 + scolb;
            __builtin_amdgcn_global_load_lds(
                (const __attribute__((address_space(1))) void*)src,
                (__attribute__((address_space(3))) void*)dst, 16, 0, 0);
        }
    };
    auto lda = [&](int half, const char* base) {
#pragma unroll
        for (int mi = 0; mi < 4; ++mi)
#pragma unroll
            for (int kk = 0; kk < 2; ++kk) {
                unsigned d = (unsigned)((wr * 128 + half * 64 + mi * 16 + lr) * 128 + kk * 64 + lg * 16);
                af[mi][kk] = *(const bf16x8*)(base + (d ^ (((d >> 7) & 7) << 4)));
            }
    };
    auto ldb = [&](bf16x8 (&bf)[2][2], int nih, const char* base) {
#pragma unroll
        for (int ni = 0; ni < 2; ++ni)
#pragma unroll
            for (int kk = 0; kk < 2; ++kk) {
                unsigned d = (unsigned)((wc * 64 + nih * 32 + ni * 16 + lr) * 128 + kk * 64 + lg * 16);
                bf[ni][kk] = *(const bf16x8*)(base + 32768 + (d ^ (((d >> 7) & 7) << 4)));
            }
    };
    auto mma = [&](bf16x8 (&bf)[2][2], int mo, int no) {
        __builtin_amdgcn_s_setprio(1);
#pragma unroll
        for (int mi = 0; mi < 4; ++mi)
#pragma unroll
            for (int ni = 0; ni < 2; ++ni)
#pragma unroll
                for (int kk = 0; kk < 2; ++kk)
                    acc[mo + mi][no + ni] = __builtin_amdgcn_mfma_f32_16x16x32_bf16(
                        af[mi][kk], bf[ni][kk], acc[mo + mi][no + ni], 0, 0, 0);
        __builtin_amdgcn_s_setprio(0);
    };

    const int nt = K >> 6;  // 16
    // prologue: tile0 -> buf0 (4 pieces), piece0 of tile1 -> buf1
#pragma unroll
    for (int p = 0; p < 4; ++p) stage(p, 0, 0);
    stage(0, 1, 1);
    asm volatile("s_waitcnt vmcnt(2)" ::: "memory");
    BAR();

    const char* b0 = smem;
    const char* b1 = smem + 65536;
    for (int i = 0; i < (nt >> 1); ++i) {
        const int T = 2 * i;
        // phase 1: A-lo + B-lo of tile T; stage piece1 of T+1 -> buf1
        lda(0, b0); ldb(bl, 0, b0);
        stage(1, T + 1, 1);
        BAR(); mma(bl, 0, 0); BAR();
        // phase 2: B-hi; stage piece2 of T+1
        ldb(bh, 1, b0);
        stage(2, T + 1, 1);
        BAR(); mma(bh, 0, 2); BAR();
        // phase 3: A-hi; stage piece3 of T+1
        lda(1, b0);
        stage(3, T + 1, 1);
        BAR(); mma(bl, 4, 0); BAR();
        // phase 4: stage piece0 of T+2 -> buf0 (buf0 reads done); counted wait
        if (T + 2 < nt) { stage(0, T + 2, 0); asm volatile("s_waitcnt vmcnt(2)" ::: "memory"); }
        else            { asm volatile("s_waitcnt vmcnt(0)" ::: "memory"); }
        BAR(); mma(bh, 4, 2); BAR();
        // phase 5: tile T+1 from buf1; stage piece1 of T+2
        lda(0, b1); ldb(bl, 0, b1);
        if (T + 2 < nt) stage(1, T + 2, 0);
        BAR(); mma(bl, 0, 0); BAR();
        // phase 6
        ldb(bh, 1, b1);
        if (T + 2 < nt) stage(2, T + 2, 0);
        BAR(); mma(bh, 0, 2); BAR();
        // phase 7
        lda(1, b1);
        if (T + 2 < nt) stage(3, T + 2, 0);
        BAR(); mma(bl, 4, 0); BAR();
        // phase 8: stage piece0 of T+3 -> buf1 (buf1 reads done); counted wait
        if (T + 3 < nt) { stage(0, T + 3, 1); asm volatile("s_waitcnt vmcnt(2)" ::: "memory"); }
        else            { asm volatile("s_waitcnt vmcnt(0)" ::: "memory"); }
        BAR(); mma(bh, 4, 2); BAR();
    }

    // epilogue: D layout col = lane&15 (n), row = (lane>>4)*4 + r (m)
#pragma unroll
    for (int mi = 0; mi < 8; ++mi)
#pragma unroll
        for (int ni = 0; ni < 4; ++ni)
#pragma unroll
            for (int r = 0; r < 4; ++r) {
                int m = m0 + wr * 128 + mi * 16 + lg * 4 + r;
                int n = n0 + wc * 64 + ni * 16 + lr;
                float v = acc[mi][ni][r];
                if (MODE == 0) {
                    int proj = n >> 10, nn = n & 1023;
                    int h = nn >> 6, d = nn & 63;
                    int bb = m >> 11, c = m & 2047;
                    if (proj == 2) {
                        // Vt layout: [bh][d][2048]
                        ((__bf16*)Out)[(size_t)2 * 8388608 +
                                       ((size_t)((bb * 16 + h) * 64 + d)) * 2048 + c] = (__bf16)v;
                    } else {
                        float scale = (proj == 0) ? 0.125f : 1.0f;
                        ((__bf16*)Out)[(size_t)proj * 8388608 +
                                       ((size_t)(bb * 16 + h) * 2048 + c) * 64 + d] =
                            (__bf16)(v * scale);
                    }
                } else {
                    ((float*)Out)[(size_t)m * N + n] = v;
                }
            }
}

// ---------------------------------------------------------------------------
// Flash attention (causal), swapped-QK^T structure.
// Grid: 1024 blocks (XCD-swizzled). Block = (bh, q-tile pair {qt, 31-qt}).
// 4 waves x 16 q-rows each. K tile + V^T tile double-buffered in LDS via
// global_load_lds with XOR-swizzled source (linear dest) + swizzled reads.
// ---------------------------------------------------------------------------
__device__ __forceinline__ unsigned swz(unsigned d) {
    return d ^ (((d >> 7) & 7) << 4);   // 128B rows; spread 16B slots across banks
}

__launch_bounds__(256, 4)
__global__ void attn_fwd(const __bf16* __restrict__ Q, const __bf16* __restrict__ K,
                         const __bf16* __restrict__ Vt, __bf16* __restrict__ Aout) {
    // LDS: K dbuf 2x8KB | Vt dbuf 2x8KB | P 4 waves x 2KB  = 40960 B
    __shared__ char smem[40960];
    const int id = blockIdx.x;
    const int vid = (id & 7) * 128 + (id >> 3);   // bijective XCD swizzle (1024%8==0)
    const int bh = vid >> 4, pr = vid & 15;
    const int w = threadIdx.x >> 6, lane = threadIdx.x & 63;
    const int lr = lane & 15, lg = lane >> 4;
    const char* Kb  = (const char*)(K  + (size_t)bh * 2048 * 64);
    const char* Vtb = (const char*)(Vt + (size_t)bh * 64 * 2048);
    const __bf16* Qb = Q + (size_t)bh * 2048 * 64;
    const int b = bh >> 4, h = bh & 15;
    char* Pb = smem + 32768 + w * 2048;

    for (int pass = 0; pass < 2; ++pass) {
        const int qt = pass ? pr : 31 - pr;       // pair work = 33 tiles, uniform
        const int q0 = qt * 64 + w * 16;
        const int nt = qt + 1;

        bf16x8 qf[2];
#pragma unroll
        for (int kk = 0; kk < 2; ++kk)
            qf[kk] = *(const bf16x8*)&Qb[(size_t)(q0 + lr) * 64 + kk * 32 + lg * 8];

        f32x4 o[4] = {};
        float m = NEG_INF, l = 0.f;

        __syncthreads();   // previous pass/compute fully done before restaging buf0
        // prologue: stage tile 0 -> buf 0 (4x global_load_lds per wave)
        {
            char* kd = smem;
            char* vd = smem + 16384;
#pragma unroll
            for (int i = 0; i < 2; ++i) {
                unsigned c = (unsigned)(w * 2 + i);
                unsigned d = c * 1024 + (unsigned)lane * 16;
                unsigned bs = swz(d);
                __builtin_amdgcn_global_load_lds(
                    (const __attribute__((address_space(1))) void*)(Kb + bs),
                    (__attribute__((address_space(3))) void*)(kd + c * 1024), 16, 0, 0);
                unsigned row = bs >> 7, colb = bs & 127;
                __builtin_amdgcn_global_load_lds(
                    (const __attribute__((address_space(1))) void*)(Vtb + (size_t)row * 4096 + colb),
                    (__attribute__((address_space(3))) void*)(vd + c * 1024), 16, 0, 0);
            }
        }

        for (int t = 0; t < nt; ++t) {
            __syncthreads();   // implicit vmcnt(0) drain: tile t resident; all waves synced
            if (t + 1 < nt) {  // prefetch t+1 while computing t
                char* kd = smem + ((t + 1) & 1) * 8192;
                char* vd = smem + 16384 + ((t + 1) & 1) * 8192;
#pragma unroll
                for (int i = 0; i < 2; ++i) {
                    unsigned c = (unsigned)(w * 2 + i);
                    unsigned d = c * 1024 + (unsigned)lane * 16;
                    unsigned bs = swz(d);
                    __builtin_amdgcn_global_load_lds(
                        (const __attribute__((address_space(1))) void*)(Kb + (size_t)(t + 1) * 8192 + bs),
                        (__attribute__((address_space(3))) void*)(kd + c * 1024), 16, 0, 0);
                    unsigned row = bs >> 7, colb = bs & 127;
                    __builtin_amdgcn_global_load_lds(
                        (const __attribute__((address_space(1))) void*)(Vtb + (size_t)row * 4096 +
                                                                       (size_t)(t + 1) * 128 + colb),
                        (__attribute__((address_space(3))) void*)(vd + c * 1024), 16, 0, 0);
                }
            }
            const char* Ks = smem + (t & 1) * 8192;
            const char* Vs = smem + 16384 + (t & 1) * 8192;
            const int k0 = t * 64;

            // S^T = K·Q^T : lane owns full row q = q0+lr; s[sub][r] = S[q][k0+sub*16+lg*4+r]
            f32x4 s[4] = {};
#pragma unroll
            for (int kk = 0; kk < 2; ++kk)
#pragma unroll
                for (int sub = 0; sub < 4; ++sub) {
                    bf16x8 kf = *(const bf16x8*)(Ks + swz((unsigned)((sub * 16 + lr) * 128 + kk * 64 + lg * 16)));
                    s[sub] = __builtin_amdgcn_mfma_f32_16x16x32_bf16(kf, qf[kk], s[sub], 0, 0, 0);
                }
            if (t == qt) {
#pragma unroll
                for (int sub = 0; sub < 4; ++sub)
#pragma unroll
                    for (int r = 0; r < 4; ++r)
                        if (k0 + sub * 16 + lg * 4 + r > q0 + lr) s[sub][r] = NEG_INF;
            }
            // online softmax: 16 local vals + 2 shuffles across lg groups
            float mloc = NEG_INF;
#pragma unroll
            for (int sub = 0; sub < 4; ++sub)
#pragma unroll
                for (int r = 0; r < 4; ++r) mloc = fmaxf(mloc, s[sub][r]);
            mloc = fmaxf(mloc, __shfl_xor(mloc, 16));
            mloc = fmaxf(mloc, __shfl_xor(mloc, 32));
            float mnew = fmaxf(m, mloc);
            float alpha = __expf(m - mnew);
            float rs = 0.f;
#pragma unroll
            for (int sub = 0; sub < 4; ++sub)
#pragma unroll
                for (int r = 0; r < 4; ++r) {
                    float p = __expf(s[sub][r] - mnew);
                    s[sub][r] = p;
                    rs += p;
                }
            rs += __shfl_xor(rs, 16);
            rs += __shfl_xor(rs, 32);
            l = l * alpha + rs;
            m = mnew;
#pragma unroll
            for (int ni = 0; ni < 4; ++ni) o[ni] *= alpha;

            // P -> per-wave LDS (vectorized b64 writes, swizzled)
#pragma unroll
            for (int sub = 0; sub < 4; ++sub) {
                bf16x4 pk;
#pragma unroll
                for (int r = 0; r < 4; ++r) pk[r] = (__bf16)s[sub][r];
                *(bf16x4*)(Pb + swz((unsigned)(lr * 128 + sub * 32 + lg * 8))) = pk;
            }
            bf16x8 pfr[2];
#pragma unroll
            for (int kk = 0; kk < 2; ++kk)
                pfr[kk] = *(const bf16x8*)(Pb + swz((unsigned)(lr * 128 + kk * 64 + lg * 16)));

            // O^T += V^T · P^T : o[ni][r] = O[q=q0+lr][d = ni*16 + lg*4 + r]
#pragma unroll
            for (int kk = 0; kk < 2; ++kk)
#pragma unroll
                for (int ni = 0; ni < 4; ++ni) {
                    bf16x8 vf = *(const bf16x8*)(Vs + swz((unsigned)((ni * 16 + lr) * 128 + kk * 64 + lg * 16)));
                    o[ni] = __builtin_amdgcn_mfma_f32_16x16x32_bf16(vf, pfr[kk], o[ni], 0, 0, 0);
                }
        }

        // epilogue: Aout[b][c=q0+lr][h*64 + ni*16 + lg*4 + r], vectorized 8B stores
        float rinv = 1.0f / l;
#pragma unroll
        for (int ni = 0; ni < 4; ++ni) {
            bf16x4 ov;
#pragma unroll
            for (int r = 0; r < 4; ++r) ov[r] = (__bf16)(o[ni][r] * rinv);
            *(bf16x4*)&Aout[((size_t)b * 2048 + q0 + lr) * 1024 + h * 64 + ni * 16 + lg * 4] = ov;
        }
    }
}

// ---------------------------------------------------------------------------
// launch
// ---------------------------------------------------------------------------
extern "C" void kernel_launch(void* const* d_in, const int* in_sizes, int n_in,
                              void* d_out, int out_size, void* d_ws, size_t ws_size,
                              hipStream_t stream) {
    const float* x  = (const float*)d_in[0];
    const float* Wk = (const float*)d_in[1];   // dict order: x, Wk, Wq, Wv, Wo
    const float* Wq = (const float*)d_in[2];
    const float* Wv = (const float*)d_in[3];
    const float* Wo = (const float*)d_in[4];

    char* ws = (char*)d_ws;
    __bf16* xb   = (__bf16*)(ws);                 // [8192][1024]        16 MB
    __bf16* wqkv = (__bf16*)(ws + 16777216);      // [3072][1024]         6 MB
    __bf16* wo_b = (__bf16*)(ws + 23068672);      // [1024][1024]         2 MB
    __bf16* qkv  = (__bf16*)(ws + 25165824);      // Q,K: [64][2048][64]; Vt: [64][64][2048]
    __bf16* aout = (__bf16*)(ws + 75497472);      // [8192][1024]        16 MB
    float* out = (float*)d_out;

    cvt_f32_bf16<<<2048, 256, 0, stream>>>(x, xb, 8388608);
    cvt_f32_bf16<<<1024, 256, 0, stream>>>(Wq, wqkv, 1048576);            // proj 0 = Q
    cvt_f32_bf16<<<1024, 256, 0, stream>>>(Wk, wqkv + 1048576, 1048576);  // proj 1 = K
    cvt_f32_bf16<<<1024, 256, 0, stream>>>(Wv, wqkv + 2097152, 1048576);  // proj 2 = V
    cvt_f32_bf16<<<1024, 256, 0, stream>>>(Wo, wo_b, 1048576);

    gemm8<0><<<dim3(12, 32), 512, 0, stream>>>(xb, wqkv, qkv, 8192, 3072, 1024);
    attn_fwd<<<dim3(1024), 256, 0, stream>>>(qkv, qkv + 8388608, qkv + 16777216, aout);
    gemm8<1><<<dim3(4, 32), 512, 0, stream>>>(aout, wo_b, out, 8192, 1024, 1024);
}

// Round 4
// 191.996 us; speedup vs baseline: 1.0638x; 1.0638x over previous
//
#include <hip/hip_runtime.h>
#include <hip/hip_bf16.h>

typedef __bf16 bf16x8 __attribute__((ext_vector_type(8)));
typedef __bf16 bf16x4 __attribute__((ext_vector_type(4)));
typedef float f32x4 __attribute__((ext_vector_type(4)));

#define NEG_INF (-__builtin_inff())

// ---------------------------------------------------------------------------
// f32 -> bf16 conversion (vectorized, grid-stride)
// ---------------------------------------------------------------------------
__global__ void cvt_f32_bf16(const float* __restrict__ src, __bf16* __restrict__ dst, int n) {
    int idx = blockIdx.x * blockDim.x + threadIdx.x;
    int stride = gridDim.x * blockDim.x;
    for (int i = idx * 4; i < n; i += stride * 4) {
        float4 v = *(const float4*)(src + i);
        bf16x4 o;
        o[0] = (__bf16)v.x; o[1] = (__bf16)v.y; o[2] = (__bf16)v.z; o[3] = (__bf16)v.w;
        *(bf16x4*)(dst + i) = o;
    }
}

// ---------------------------------------------------------------------------
// m97-structure GEMM: 128x128 tile, BK=64, 256 threads (4 waves 2x2),
// SINGLE-buffer linear LDS (As 16KB | Bs 16KB = 32KB -> 3 blocks/CU),
// global_load_lds width=16 staging, 2 x __syncthreads per K-step.
// out[m][n] = sum_k A[m][k]*B[n][k]  (A:[M][K], B:[N][K], bf16).
// MODE 0: bf16 out scattered to QKV layout; Q scaled 1/8; V transposed.
// MODE 1: f32 out row-major [M][N].
// ---------------------------------------------------------------------------
template <int MODE>
__launch_bounds__(256, 3)
__global__ void gemm_bt(const __bf16* __restrict__ A, const __bf16* __restrict__ Bm,
                        void* __restrict__ Out, int M, int N, int K) {
    __shared__ __align__(1024) char smem[32768];   // As [128][64] | Bs [128][64]
    const int tid = threadIdx.x;
    const int w = tid >> 6, lane = tid & 63;
    const int lr = lane & 15, lg = lane >> 4;
    const int wm0 = (w >> 1) * 64, wn0 = (w & 1) * 64;

    // bijective XCD swizzle (nwg % 8 == 0 for both call sites)
    const int nbx = gridDim.x;
    int id = blockIdx.y * nbx + blockIdx.x;
    int q8 = (nbx * gridDim.y) >> 3;
    int vid = (id & 7) * q8 + (id >> 3);
    const int m0 = (vid / nbx) * 128, n0 = (vid % nbx) * 128;

    const char* Ab = (const char*)A;
    const char* Bb = (const char*)Bm;

    f32x4 acc[4][4] = {};

    // staging geometry: chunk c = w*4+r covers LDS bytes [c*1024, c*1024+1024)
    // = rows c*8 .. c*8+7 of a [128][64] bf16 tile; lane writes 16B at
    // row c*8 + lane/8, col16 = lane%8. Global src per-lane, LDS dest uniform.
    const int s_row_in_chunk = lane >> 3;   // 0..7
    const int s_col16 = lane & 7;           // 0..7

    const int nt = K >> 6;
    for (int t = 0; t < nt; ++t) {
        // issue 8 global_load_lds (4 for A, 4 for B)
#pragma unroll
        for (int r = 0; r < 4; ++r) {
            int c = w * 4 + r;                       // wave-uniform chunk 0..15
            int row = c * 8 + s_row_in_chunk;
            const char* srcA = Ab + ((size_t)(m0 + row) * K + t * 64) * 2 + s_col16 * 16;
            const char* srcB = Bb + ((size_t)(n0 + row) * K + t * 64) * 2 + s_col16 * 16;
            __builtin_amdgcn_global_load_lds(
                (const __attribute__((address_space(1))) void*)srcA,
                (__attribute__((address_space(3))) void*)(smem + c * 1024), 16, 0, 0);
            __builtin_amdgcn_global_load_lds(
                (const __attribute__((address_space(1))) void*)srcB,
                (__attribute__((address_space(3))) void*)(smem + 16384 + c * 1024), 16, 0, 0);
        }
        __syncthreads();   // drains vmcnt(0): tile resident

#pragma unroll
        for (int kk = 0; kk < 2; ++kk) {
            bf16x8 af[4], bf[4];
#pragma unroll
            for (int mi = 0; mi < 4; ++mi)
                af[mi] = *(const bf16x8*)(smem + (wm0 + mi * 16 + lr) * 128 + kk * 64 + lg * 16);
#pragma unroll
            for (int ni = 0; ni < 4; ++ni)
                bf[ni] = *(const bf16x8*)(smem + 16384 + (wn0 + ni * 16 + lr) * 128 + kk * 64 + lg * 16);
            __builtin_amdgcn_s_setprio(1);
#pragma unroll
            for (int mi = 0; mi < 4; ++mi)
#pragma unroll
                for (int ni = 0; ni < 4; ++ni)
                    acc[mi][ni] = __builtin_amdgcn_mfma_f32_16x16x32_bf16(
                        af[mi], bf[ni], acc[mi][ni], 0, 0, 0);
            __builtin_amdgcn_s_setprio(0);
        }
        __syncthreads();   // all reads done before next stage overwrites
    }

    // epilogue: D layout col = lane&15 (n), row = (lane>>4)*4 + r (m)
#pragma unroll
    for (int mi = 0; mi < 4; ++mi)
#pragma unroll
        for (int ni = 0; ni < 4; ++ni)
#pragma unroll
            for (int r = 0; r < 4; ++r) {
                int m = m0 + wm0 + mi * 16 + lg * 4 + r;
                int n = n0 + wn0 + ni * 16 + lr;
                float v = acc[mi][ni][r];
                if (MODE == 0) {
                    int proj = n >> 10, nn = n & 1023;
                    int h = nn >> 6, d = nn & 63;
                    int bb = m >> 11, c = m & 2047;
                    if (proj == 2) {
                        // Vt layout: [bh][d][2048]
                        ((__bf16*)Out)[(size_t)2 * 8388608 +
                                       ((size_t)((bb * 16 + h) * 64 + d)) * 2048 + c] = (__bf16)v;
                    } else {
                        float scale = (proj == 0) ? 0.125f : 1.0f;
                        ((__bf16*)Out)[(size_t)proj * 8388608 +
                                       ((size_t)(bb * 16 + h) * 2048 + c) * 64 + d] =
                            (__bf16)(v * scale);
                    }
                } else {
                    ((float*)Out)[(size_t)m * N + n] = v;
                }
            }
}

// ---------------------------------------------------------------------------
// Flash attention (causal), swapped-QK^T structure.
// Grid: 1024 blocks (XCD-swizzled). Block = (bh, q-tile pair {qt, 31-qt}).
// 4 waves x 16 q-rows each. K tile + V^T tile double-buffered in LDS via
// global_load_lds with XOR-swizzled source (linear dest) + swizzled reads.
// ---------------------------------------------------------------------------
__device__ __forceinline__ unsigned swz(unsigned d) {
    return d ^ (((d >> 7) & 7) << 4);   // 128B rows; spread 16B slots across banks
}

__launch_bounds__(256, 4)
__global__ void attn_fwd(const __bf16* __restrict__ Q, const __bf16* __restrict__ K,
                         const __bf16* __restrict__ Vt, __bf16* __restrict__ Aout) {
    // LDS: K dbuf 2x8KB | Vt dbuf 2x8KB | P 4 waves x 2KB  = 40960 B
    __shared__ char smem[40960];
    const int id = blockIdx.x;
    const int vid = (id & 7) * 128 + (id >> 3);   // bijective XCD swizzle (1024%8==0)
    const int bh = vid >> 4, pr = vid & 15;
    const int w = threadIdx.x >> 6, lane = threadIdx.x & 63;
    const int lr = lane & 15, lg = lane >> 4;
    const char* Kb  = (const char*)(K  + (size_t)bh * 2048 * 64);
    const char* Vtb = (const char*)(Vt + (size_t)bh * 64 * 2048);
    const __bf16* Qb = Q + (size_t)bh * 2048 * 64;
    const int b = bh >> 4, h = bh & 15;
    char* Pb = smem + 32768 + w * 2048;

    for (int pass = 0; pass < 2; ++pass) {
        const int qt = pass ? pr : 31 - pr;       // pair work = 33 tiles, uniform
        const int q0 = qt * 64 + w * 16;
        const int nt = qt + 1;

        bf16x8 qf[2];
#pragma unroll
        for (int kk = 0; kk < 2; ++kk)
            qf[kk] = *(const bf16x8*)&Qb[(size_t)(q0 + lr) * 64 + kk * 32 + lg * 8];

        f32x4 o[4] = {};
        float m = NEG_INF, l = 0.f;

        __syncthreads();   // previous pass/compute fully done before restaging buf0
        // prologue: stage tile 0 -> buf 0 (4x global_load_lds per wave)
        {
            char* kd = smem;
            char* vd = smem + 16384;
#pragma unroll
            for (int i = 0; i < 2; ++i) {
                unsigned c = (unsigned)(w * 2 + i);
                unsigned d = c * 1024 + (unsigned)lane * 16;
                unsigned bs = swz(d);
                __builtin_amdgcn_global_load_lds(
                    (const __attribute__((address_space(1))) void*)(Kb + bs),
                    (__attribute__((address_space(3))) void*)(kd + c * 1024), 16, 0, 0);
                unsigned row = bs >> 7, colb = bs & 127;
                __builtin_amdgcn_global_load_lds(
                    (const __attribute__((address_space(1))) void*)(Vtb + (size_t)row * 4096 + colb),
                    (__attribute__((address_space(3))) void*)(vd + c * 1024), 16, 0, 0);
            }
        }

        for (int t = 0; t < nt; ++t) {
            __syncthreads();   // implicit vmcnt(0) drain: tile t resident; all waves synced
            if (t + 1 < nt) {  // prefetch t+1 while computing t
                char* kd = smem + ((t + 1) & 1) * 8192;
                char* vd = smem + 16384 + ((t + 1) & 1) * 8192;
#pragma unroll
                for (int i = 0; i < 2; ++i) {
                    unsigned c = (unsigned)(w * 2 + i);
                    unsigned d = c * 1024 + (unsigned)lane * 16;
                    unsigned bs = swz(d);
                    __builtin_amdgcn_global_load_lds(
                        (const __attribute__((address_space(1))) void*)(Kb + (size_t)(t + 1) * 8192 + bs),
                        (__attribute__((address_space(3))) void*)(kd + c * 1024), 16, 0, 0);
                    unsigned row = bs >> 7, colb = bs & 127;
                    __builtin_amdgcn_global_load_lds(
                        (const __attribute__((address_space(1))) void*)(Vtb + (size_t)row * 4096 +
                                                                       (size_t)(t + 1) * 128 + colb),
                        (__attribute__((address_space(3))) void*)(vd + c * 1024), 16, 0, 0);
                }
            }
            const char* Ks = smem + (t & 1) * 8192;
            const char* Vs = smem + 16384 + (t & 1) * 8192;
            const int k0 = t * 64;

            // S^T = K·Q^T : lane owns full row q = q0+lr; s[sub][r] = S[q][k0+sub*16+lg*4+r]
            f32x4 s[4] = {};
#pragma unroll
            for (int kk = 0; kk < 2; ++kk)
#pragma unroll
                for (int sub = 0; sub < 4; ++sub) {
                    bf16x8 kf = *(const bf16x8*)(Ks + swz((unsigned)((sub * 16 + lr) * 128 + kk * 64 + lg * 16)));
                    s[sub] = __builtin_amdgcn_mfma_f32_16x16x32_bf16(kf, qf[kk], s[sub], 0, 0, 0);
                }
            if (t == qt) {
#pragma unroll
                for (int sub = 0; sub < 4; ++sub)
#pragma unroll
                    for (int r = 0; r < 4; ++r)
                        if (k0 + sub * 16 + lg * 4 + r > q0 + lr) s[sub][r] = NEG_INF;
            }
            // online softmax: 16 local vals + 2 shuffles across lg groups
            float mloc = NEG_INF;
#pragma unroll
            for (int sub = 0; sub < 4; ++sub)
#pragma unroll
                for (int r = 0; r < 4; ++r) mloc = fmaxf(mloc, s[sub][r]);
            mloc = fmaxf(mloc, __shfl_xor(mloc, 16));
            mloc = fmaxf(mloc, __shfl_xor(mloc, 32));
            float mnew = fmaxf(m, mloc);
            float alpha = __expf(m - mnew);
            float rs = 0.f;
#pragma unroll
            for (int sub = 0; sub < 4; ++sub)
#pragma unroll
                for (int r = 0; r < 4; ++r) {
                    float p = __expf(s[sub][r] - mnew);
                    s[sub][r] = p;
                    rs += p;
                }
            rs += __shfl_xor(rs, 16);
            rs += __shfl_xor(rs, 32);
            l = l * alpha + rs;
            m = mnew;
#pragma unroll
            for (int ni = 0; ni < 4; ++ni) o[ni] *= alpha;

            // P -> per-wave LDS (vectorized b64 writes, swizzled)
#pragma unroll
            for (int sub = 0; sub < 4; ++sub) {
                bf16x4 pk;
#pragma unroll
                for (int r = 0; r < 4; ++r) pk[r] = (__bf16)s[sub][r];
                *(bf16x4*)(Pb + swz((unsigned)(lr * 128 + sub * 32 + lg * 8))) = pk;
            }
            bf16x8 pfr[2];
#pragma unroll
            for (int kk = 0; kk < 2; ++kk)
                pfr[kk] = *(const bf16x8*)(Pb + swz((unsigned)(lr * 128 + kk * 64 + lg * 16)));

            // O^T += V^T · P^T : o[ni][r] = O[q=q0+lr][d = ni*16 + lg*4 + r]
#pragma unroll
            for (int kk = 0; kk < 2; ++kk)
#pragma unroll
                for (int ni = 0; ni < 4; ++ni) {
                    bf16x8 vf = *(const bf16x8*)(Vs + swz((unsigned)((ni * 16 + lr) * 128 + kk * 64 + lg * 16)));
                    o[ni] = __builtin_amdgcn_mfma_f32_16x16x32_bf16(vf, pfr[kk], o[ni], 0, 0, 0);
                }
        }

        // epilogue: Aout[b][c=q0+lr][h*64 + ni*16 + lg*4 + r], vectorized 8B stores
        float rinv = 1.0f / l;
#pragma unroll
        for (int ni = 0; ni < 4; ++ni) {
            bf16x4 ov;
#pragma unroll
            for (int r = 0; r < 4; ++r) ov[r] = (__bf16)(o[ni][r] * rinv);
            *(bf16x4*)&Aout[((size_t)b * 2048 + q0 + lr) * 1024 + h * 64 + ni * 16 + lg * 4] = ov;
        }
    }
}

// ---------------------------------------------------------------------------
// launch
// ---------------------------------------------------------------------------
extern "C" void kernel_launch(void* const* d_in, const int* in_sizes, int n_in,
                              void* d_out, int out_size, void* d_ws, size_t ws_size,
                              hipStream_t stream) {
    const float* x  = (const float*)d_in[0];
    const float* Wk = (const float*)d_in[1];   // dict order: x, Wk, Wq, Wv, Wo
    const float* Wq = (const float*)d_in[2];
    const float* Wv = (const float*)d_in[3];
    const float* Wo = (const float*)d_in[4];

    char* ws = (char*)d_ws;
    __bf16* xb   = (__bf16*)(ws);                 // [8192][1024]        16 MB
    __bf16* wqkv = (__bf16*)(ws + 16777216);      // [3072][1024]         6 MB
    __bf16* wo_b = (__bf16*)(ws + 23068672);      // [1024][1024]         2 MB
    __bf16* qkv  = (__bf16*)(ws + 25165824);      // Q,K: [64][2048][64]; Vt: [64][64][2048]
    __bf16* aout = (__bf16*)(ws + 75497472);      // [8192][1024]        16 MB
    float* out = (float*)d_out;

    cvt_f32_bf16<<<2048, 256, 0, stream>>>(x, xb, 8388608);
    cvt_f32_bf16<<<1024, 256, 0, stream>>>(Wq, wqkv, 1048576);            // proj 0 = Q
    cvt_f32_bf16<<<1024, 256, 0, stream>>>(Wk, wqkv + 1048576, 1048576);  // proj 1 = K
    cvt_f32_bf16<<<1024, 256, 0, stream>>>(Wv, wqkv + 2097152, 1048576);  // proj 2 = V
    cvt_f32_bf16<<<1024, 256, 0, stream>>>(Wo, wo_b, 1048576);

    gemm_bt<0><<<dim3(24, 64), 256, 0, stream>>>(xb, wqkv, qkv, 8192, 3072, 1024);
    attn_fwd<<<dim3(1024), 256, 0, stream>>>(qkv, qkv + 8388608, qkv + 16777216, aout);
    gemm_bt<1><<<dim3(8, 64), 256, 0, stream>>>(aout, wo_b, out, 8192, 1024, 1024);
}